// Round 10
// baseline (849.832 us; speedup 1.0000x reference)
//
#include <hip/hip_runtime.h>

typedef unsigned short ushort_t;
typedef unsigned int uint32;
typedef __attribute__((ext_vector_type(8))) short short8;
typedef __attribute__((ext_vector_type(4))) short short4v;
typedef __attribute__((ext_vector_type(4))) float floatx4;
typedef __attribute__((ext_vector_type(2))) float float2v;
typedef __attribute__((ext_vector_type(8))) int intx8;

#define B_    128
#define T_    512
#define H_    256
#define H2_   512
#define LIN_  200
#define LINP_ 224
#define G4_   1024
#define SP_   58
#define BT_   (B_*T_)

// ---------- ws layout (bytes) ----------
#define OFF_LS     0UL          // int  [B,T]      262144
#define OFF_LP     262144UL     // int  [B,T]      262144
#define OFF_WID    524288UL     // int  [B,T]      262144
#define OFF_INV    786432UL     // f32  [B,T]      262144
#define OFF_CSAVE  1048576UL    // f32  [32][16][64] 131072 (k_rec2 c handoff)
#define OFF_HSAVE  1179648UL    // fp8  [128][256]   32768 (k_rec2 h handoff)
#define OFF_POSW   1212416UL    // f32  [32][200]   25600
#define OFF_WLW    1238016UL    // f32  [8][200]     6400
#define OFF_BIASG  1244416UL    // f32  [1024]       4096
#define OFF_WHH    1248512UL    // fp8  [1024][256] 262144
#define OFF_WIH    1772800UL    // bf16 [1024][224] 458752
#define OFF_WENC   2231552UL    // bf16 [200][512]  204800
#define OFF_COMBW  2436352UL    // bf16 [58][768]    89088
#define OFF_ECW    2525440UL    // bf16 [65536][200] time-major rows (t*128+b)
#define OFF_Z      28739840UL   // bf16 [65536][224] time-major rows
#define OFF_GPERM  58099968UL   // bf16 swizzled [512][32 blk][16 w][4 g][16 u][4 qd]
#define OFF_VBF    192317696UL  // bf16 [65536][768] time-major rows (0:256 hs, 256:768 enc)

__device__ __forceinline__ ushort_t f2bf(float x){
  uint32 u = __float_as_uint(x);
  u += 0x7fffu + ((u >> 16) & 1u);
  return (ushort_t)(u >> 16);
}
__device__ __forceinline__ float bf2f(ushort_t v){
  return __uint_as_float(((uint32)v) << 16);
}
// fast sigmoid/tanh (exp2-based __expf + v_rcp); |err| ~1e-5, way inside bf16
__device__ __forceinline__ float fsig(float x){
  return __builtin_amdgcn_rcpf(1.0f + __expf(-x));
}
__device__ __forceinline__ float ftanh(float x){
  return 1.0f - 2.0f * __builtin_amdgcn_rcpf(1.0f + __expf(2.0f * x));
}

// ---------- scan: last_sep / wordlen / last_pos, parallel Hillis-Steele ----------
__global__ __launch_bounds__(512) void k_scan(const int* __restrict__ sep, const int* __restrict__ pos_ids,
                       int* __restrict__ ls, int* __restrict__ lp,
                       int* __restrict__ wid, float* __restrict__ inv){
  int b = blockIdx.x, t = threadIdx.x;
  __shared__ int sm[512];
  int v = (sep[b*T_ + t] > 0) ? t : 0;
  sm[t] = v;
  __syncthreads();
  #pragma unroll
  for (int off = 1; off < 512; off <<= 1){
    int o = (t >= off) ? sm[t - off] : 0;
    __syncthreads();
    v = (o > v) ? o : v;
    sm[t] = v;
    __syncthreads();
  }
  int l = (t == 0) ? 0 : sm[t - 1];      // last sep strictly before t
  int wlen = t - l;
  int wsv  = (wlen < 1) ? 1 : wlen;
  ls[b*T_ + t]  = l;
  lp[b*T_ + t]  = pos_ids[b*T_ + l];
  wid[b*T_ + t] = (wsv > 7) ? 7 : wsv;
  inv[b*T_ + t] = 1.0f / (float)wsv;
}

// ---------- enc -> bf16 into vbf[t*128+b][256:768] ----------
__global__ __launch_bounds__(256) void k_encbf(const float* __restrict__ enc, ushort_t* __restrict__ vbf){
  const long total = (long)BT_ * 128;          // float4 count (65536 rows x 128)
  for (long i = (long)blockIdx.x * 256 + threadIdx.x; i < total; i += 2048L * 256){
    floatx4 v = ((const floatx4*)enc)[i];
    long row = i >> 7;                         // b*512 + t (enc layout)
    int c4 = (int)(i & 127);
    int b = (int)(row >> 9), t = (int)(row & (T_-1));
    short4v pk;
    pk[0] = (short)f2bf(v[0]); pk[1] = (short)f2bf(v[1]);
    pk[2] = (short)f2bf(v[2]); pk[3] = (short)f2bf(v[3]);
    *(short4v*)(void*)(vbf + ((long)t * B_ + b) * 768 + 256 + c4*4) = pk;
  }
}

// ---------- small precomputes / weight conversions ----------
__global__ __launch_bounds__(256) void k_small(
    const float* __restrict__ pos_emb, const float* __restrict__ wl_emb,
    const float* __restrict__ fcW, const float* __restrict__ W_ih,
    const float* __restrict__ W_hh, const float* __restrict__ b_ih,
    const float* __restrict__ b_hh, const float* __restrict__ combW,
    float* __restrict__ posW, float* __restrict__ wlW, float* __restrict__ biasg,
    char* __restrict__ whh8, ushort_t* __restrict__ wih,
    ushort_t* __restrict__ wenc, ushort_t* __restrict__ combwb){
  int idx = blockIdx.x * 256 + threadIdx.x;
  if (idx < 6400){
    int p = idx / 200, l = idx % 200;
    float s = 0.f;
    for (int d = 0; d < 50; d++) s += pos_emb[p*50 + d] * fcW[l*582 + d];
    posW[idx] = s; return;
  }
  idx -= 6400;
  if (idx < 1600){
    int w = idx / 200, l = idx % 200;
    float s = 0.f;
    for (int d = 0; d < 20; d++) s += wl_emb[w*20 + d] * fcW[l*582 + 562 + d];
    wlW[idx] = s; return;
  }
  idx -= 1600;
  if (idx < 1024){ biasg[idx] = b_ih[idx] + b_hh[idx]; return; }
  idx -= 1024;
  if (idx < 262144){
    int p8 = __builtin_amdgcn_cvt_pk_fp8_f32(W_hh[idx], W_hh[idx], 0, false);
    whh8[idx] = (char)(p8 & 0xff);
    return;
  }
  idx -= 262144;
  if (idx < 229376){
    int n = idx / 224, k = idx % 224;
    wih[idx] = (k < 200) ? f2bf(W_ih[n*200 + k]) : (ushort_t)0;
    return;
  }
  idx -= 229376;
  if (idx < 102400){
    int l = idx / 512, c = idx % 512;
    wenc[idx] = f2bf(fcW[l*582 + 50 + c]); return;
  }
  idx -= 102400;
  if (idx < 44544){ combwb[idx] = f2bf(combW[idx]); return; }
}

// ---------- 128x256 8-wave double-buffered bf16 GEMM (mid GEMMs, short K) ----------
// One vmcnt(0)+barrier per K-step, prefetch issued before compute (T3-minimal).
// Linear LDS (gload_lds dst) + XOR swizzle byte^=((row>>1)&3)<<4 applied BOTH sides
// (pre-swizzled source granule + swizzled read addr, rule #21). Harness-verified r9.
template<int EPI>
__global__ __launch_bounds__(512, 2) void k_big(
    const ushort_t* __restrict__ A, long lda,
    const ushort_t* __restrict__ Bm, int K, int Nvalid,
    void* __restrict__ Cout, const float* __restrict__ bias){
  __shared__ __attribute__((aligned(16))) ushort_t As[2][128][32];
  __shared__ __attribute__((aligned(16))) ushort_t Bs[2][256][32];
  int tid  = threadIdx.x;
  int lane = tid & 63, w = tid >> 6;          // 8 waves
  int u = lane & 15, quad = lane >> 4;
  int wm = w >> 2, wn = w & 3;                // 2x4 wave grid, 64x64 per wave
  long m0 = (long)blockIdx.y * 128;
  int  n0 = blockIdx.x * 256;
  int sr = lane >> 2;
  int gp = lane & 3;
  int gl = gp ^ ((sr >> 1) & 3);              // logical granule this lane fetches
  int arow = w*16 + sr;
  const ushort_t* asrc = A + (m0 + arow) * lda + gl*8;
  int brow = w*32 + sr;
  const ushort_t* bsrc0 = Bm + (long)(n0 + brow) * K + gl*8;
  const ushort_t* bsrc1 = Bm + (long)(n0 + brow + 16) * K + gl*8;
  floatx4 acc[4][4] = {};

#define STAGEK(buf, kk) do{ \
    __builtin_amdgcn_global_load_lds( \
        (const __attribute__((address_space(1))) void*)(asrc + (kk)), \
        (__attribute__((address_space(3))) void*)((char*)&As[buf][0][0] + w*1024), 16, 0, 0); \
    __builtin_amdgcn_global_load_lds( \
        (const __attribute__((address_space(1))) void*)(bsrc0 + (kk)), \
        (__attribute__((address_space(3))) void*)((char*)&Bs[buf][0][0] + w*2048), 16, 0, 0); \
    __builtin_amdgcn_global_load_lds( \
        (const __attribute__((address_space(1))) void*)(bsrc1 + (kk)), \
        (__attribute__((address_space(3))) void*)((char*)&Bs[buf][0][0] + w*2048 + 1024), 16, 0, 0); \
  }while(0)

  STAGEK(0, 0);
  asm volatile("s_waitcnt vmcnt(0)\n\ts_barrier" ::: "memory");
  int nk = K >> 5;
  int cur = 0;
  for (int ks = 0; ks < nk; ks++){
    if (ks + 1 < nk) STAGEK(cur ^ 1, (ks + 1) << 5);
    short8 af[4], bfv[4];
    #pragma unroll
    for (int mi = 0; mi < 4; mi++){
      int row = wm*64 + mi*16 + u;
      int off = (row*64 + quad*16) ^ (((row >> 1) & 3) << 4);
      af[mi] = *(const short8*)(const void*)((const char*)&As[cur][0][0] + off);
    }
    #pragma unroll
    for (int ni = 0; ni < 4; ni++){
      int row = wn*64 + ni*16 + u;
      int off = (row*64 + quad*16) ^ (((row >> 1) & 3) << 4);
      bfv[ni] = *(const short8*)(const void*)((const char*)&Bs[cur][0][0] + off);
    }
    #pragma unroll
    for (int mi = 0; mi < 4; mi++)
      #pragma unroll
      for (int ni = 0; ni < 4; ni++)
        acc[mi][ni] = __builtin_amdgcn_mfma_f32_16x16x32_bf16(af[mi], bfv[ni], acc[mi][ni], 0, 0, 0);
    asm volatile("s_waitcnt vmcnt(0)\n\ts_barrier" ::: "memory");
    cur ^= 1;
  }
#undef STAGEK

  if (EPI == 1){
    #pragma unroll
    for (int mi = 0; mi < 4; mi++){
      #pragma unroll
      for (int ni = 0; ni < 4; ni++){
        long mm = m0 + wm*64 + mi*16 + quad*4;   // 4 r's = 4 consecutive b (qd 0..3)
        int n = n0 + wn*64 + ni*16 + u;
        float bv = bias[n];
        int t = (int)(mm >> 7);
        int b = (int)(mm & 127);
        int blk = b >> 2;                         // b % 4 == 0 here
        int g = n >> 8, j = n & 255, ut = j & 15, jt = j >> 4;
        long idx = ((((long)t*32 + blk)*16 + jt)*4 + g)*64 + ut*4;
        short4v pk;
        #pragma unroll
        for (int r = 0; r < 4; r++) pk[r] = (short)f2bf(acc[mi][ni][r] + bv);
        *(short4v*)(void*)((ushort_t*)Cout + idx) = pk;
      }
    }
  } else {
    for (int mi = 0; mi < 4; mi++){
      for (int ni = 0; ni < 4; ni++){
        int n = n0 + wn*64 + ni*16 + u;
        if (n < Nvalid){
          #pragma unroll
          for (int r = 0; r < 4; r++){
            long m = m0 + wm*64 + mi*16 + quad*4 + r;
            ((ushort_t*)Cout)[m * Nvalid + n] = f2bf(acc[mi][ni][r]);
          }
        }
      }
    }
  }
}

// ---------- logits GEMM: BM=256 x BN=64, 8 waves (4x2), dbuf + gload_lds ----------
// Replaces the 64sq template (4 MFMA/SIMD per 2 barriers, full 100MB vbf read).
// 16 MFMA/SIMD per single barrier; same XOR swizzle as k_big. B rows 58..63 read
// in-bounds garbage (possibly NaN) feeding only masked n>=58 columns.
__global__ __launch_bounds__(512, 2) void k_logit(
    const ushort_t* __restrict__ A,          // vbf [65536][768]
    const ushort_t* __restrict__ Bm,         // combwb [58][768]
    float* __restrict__ Cout, const int* __restrict__ len){
  __shared__ __attribute__((aligned(16))) ushort_t As[2][256][32];
  __shared__ __attribute__((aligned(16))) ushort_t Bs[2][64][32];
  int tid  = threadIdx.x;
  int lane = tid & 63, w = tid >> 6;          // 8 waves
  int u = lane & 15, quad = lane >> 4;
  int wm = w >> 1, wn = w & 1;                // 4x2 wave grid, 64x32 per wave
  long m0 = (long)blockIdx.x * 256;
  int sr = lane >> 2;
  int gp = lane & 3;
  int gl = gp ^ ((sr >> 1) & 3);
  const ushort_t* asrc0 = A + (m0 + w*32 + sr) * 768 + gl*8;
  const ushort_t* asrc1 = A + (m0 + w*32 + 16 + sr) * 768 + gl*8;
  const ushort_t* bsrc  = Bm + (long)(w*16 + sr) * 768 + gl*8;   // waves 0..3 only
  floatx4 acc[4][2] = {};

#define STG(buf, kk) do{ \
    __builtin_amdgcn_global_load_lds( \
        (const __attribute__((address_space(1))) void*)(asrc0 + (kk)), \
        (__attribute__((address_space(3))) void*)((char*)&As[buf][0][0] + w*2048), 16, 0, 0); \
    __builtin_amdgcn_global_load_lds( \
        (const __attribute__((address_space(1))) void*)(asrc1 + (kk)), \
        (__attribute__((address_space(3))) void*)((char*)&As[buf][0][0] + w*2048 + 1024), 16, 0, 0); \
    if (w < 4) __builtin_amdgcn_global_load_lds( \
        (const __attribute__((address_space(1))) void*)(bsrc + (kk)), \
        (__attribute__((address_space(3))) void*)((char*)&Bs[buf][0][0] + w*1024), 16, 0, 0); \
  }while(0)

  STG(0, 0);
  asm volatile("s_waitcnt vmcnt(0)\n\ts_barrier" ::: "memory");
  int cur = 0;
  for (int ks = 0; ks < 24; ks++){
    if (ks + 1 < 24) STG(cur ^ 1, (ks + 1) << 5);
    short8 af[4], bfv[2];
    #pragma unroll
    for (int mi = 0; mi < 4; mi++){
      int row = wm*64 + mi*16 + u;
      int off = (row*64 + quad*16) ^ (((row >> 1) & 3) << 4);
      af[mi] = *(const short8*)(const void*)((const char*)&As[cur][0][0] + off);
    }
    #pragma unroll
    for (int ni = 0; ni < 2; ni++){
      int row = wn*32 + ni*16 + u;
      int off = (row*64 + quad*16) ^ (((row >> 1) & 3) << 4);
      bfv[ni] = *(const short8*)(const void*)((const char*)&Bs[cur][0][0] + off);
    }
    #pragma unroll
    for (int mi = 0; mi < 4; mi++)
      #pragma unroll
      for (int ni = 0; ni < 2; ni++)
        acc[mi][ni] = __builtin_amdgcn_mfma_f32_16x16x32_bf16(af[mi], bfv[ni], acc[mi][ni], 0, 0, 0);
    asm volatile("s_waitcnt vmcnt(0)\n\ts_barrier" ::: "memory");
    cur ^= 1;
  }
#undef STG

  #pragma unroll
  for (int mi = 0; mi < 4; mi++){
    #pragma unroll
    for (int ni = 0; ni < 2; ni++){
      int n = wn*32 + ni*16 + u;
      if (n < SP_){
        #pragma unroll
        for (int r = 0; r < 4; r++){
          long m = m0 + wm*64 + mi*16 + quad*4 + r;
          int t = (int)(m >> 7); int b = (int)(m & 127);
          float o = (t < len[b]) ? acc[mi][ni][r] : 0.0f;
          if (t == 0 && n == 0) o = -1e30f;
          Cout[((long)b * T_ + t) * SP_ + n] = o;
        }
      }
    }
  }
}

// ---------- exclusive cumsum over t, in place on E (bf16, time-major rows) ----------
__global__ __launch_bounds__(256) void k_cum200(ushort_t* __restrict__ E){
  int b = blockIdx.x;
  int c = threadIdx.x;
  if (c >= LIN_) return;
  float acc = 0.f;
  ushort_t* p = E + (long)b * LIN_ + c;      // row (t*128+b)
  const long rs = (long)B_ * LIN_;           // per-t stride
  for (int t0 = 0; t0 < T_; t0 += 16){
    float vv[16];
    #pragma unroll
    for (int i = 0; i < 16; i++) vv[i] = bf2f(p[i*rs]);
    #pragma unroll
    for (int i = 0; i < 16; i++){ p[i*rs] = f2bf(acc); acc += vv[i]; }
    p += 16*rs;
  }
}

// ---------- z = tanh((CW[t]-CW[ls])*inv + posW + wlW + b), t=0 -> 0, pad K to 224 ----------
__global__ __launch_bounds__(256) void k_z(
    const ushort_t* __restrict__ CW, const int* __restrict__ ls, const int* __restrict__ lp,
    const int* __restrict__ wid, const float* __restrict__ inv,
    const float* __restrict__ posW, const float* __restrict__ wlW,
    const float* __restrict__ fcb, ushort_t* __restrict__ zbf){
  int l = threadIdx.x;
  if (l >= LINP_) return;
  float fb = (l < LIN_) ? fcb[l] : 0.f;
  #pragma unroll
  for (int i = 0; i < 8; i++){
    int m = blockIdx.x * 8 + i;       // time-major row t*128+b
    int t = m >> 7;
    int b = m & 127;
    int ar = b * T_ + t;              // b-major aux index
    ushort_t o = 0;
    if (t != 0 && l < LIN_){
      int lsv = ls[ar];
      float x = bf2f(CW[(long)m * LIN_ + l]) - bf2f(CW[((long)lsv * B_ + b) * LIN_ + l]);
      x = x * inv[ar] + posW[lp[ar]*LIN_ + l] + wlW[wid[ar]*LIN_ + l] + fb;
      o = f2bf(ftanh(x));
    }
    zbf[(long)m * LINP_ + l] = o;
  }
}

// ---------- LSTM recurrence, split into two 256-step phases ----------
// Round-5 plateau body unchanged. Split hands off c (f32, csave) and h(255)
// (fp8 packed rows, hsave) between phases. Purpose: (a) each half ~220us so the
// rocprof top-5 window exposes the tail kernels; (b) negligible cost (~+5us).
template<int PHASE>
__global__ __launch_bounds__(1024, 4) void k_rec2(
    const ushort_t* __restrict__ Gperm, const char* __restrict__ whh8,
    ushort_t* __restrict__ vbf, float* __restrict__ csave, char* __restrict__ hsave){
  int blk  = blockIdx.x;                      // 0..31: batches blk*4 .. blk*4+3
  int tid  = threadIdx.x;
  int lane = tid & 63, w = tid >> 6;          // w in [0,16): hidden j-tile
  int u = lane & 15, quad = lane >> 4;        // quad = local batch index
  __shared__ __attribute__((aligned(16))) char h8[2][16][272];   // row stride 272
  for (int i = tid; i < (int)(sizeof(h8)/4); i += 1024) ((int*)h8)[i] = 0;

  // W_hh fp8 B-fragments (MX K=128): gate g, cols w*16+u; pinned in VGPRs.
  intx8 wfx[4][2];
  #pragma unroll
  for (int g = 0; g < 4; g++){
    int grow = g*256 + w*16 + u;
    #pragma unroll
    for (int kc = 0; kc < 2; kc++){
      intx8 v = *(const intx8*)(const void*)(whh8 + (long)grow*256 + kc*128 + quad*32);
      asm volatile("" : "+v"(v));
      wfx[g][kc] = v;
    }
  }
  float c_reg;
  floatx4 acc[4] = {};   // element 0 rebuilt each step; elements 1..3 stay 0 forever
  const int T0 = PHASE ? (T_/2) : 0;
  const int T1 = PHASE ? T_ : (T_/2);
  if (PHASE == 0){
    c_reg = 0.f;
    __syncthreads();                          // h8 zero-init visible
  } else {
    c_reg = csave[((blk*16 + w) << 6) + lane];
    __syncthreads();                          // zero-init done before row restore
    if (w < 4)
      ((uint32*)&h8[0][4*w][0])[lane] = ((const uint32*)(hsave + (blk*4 + w)*256))[lane];
    __syncthreads();                          // h(255) restored
  }

  // Gperm[t][blk][w][g][u][qd]: lane (quad,u) reads gate g at g*64 + u*4 + quad
  const ushort_t* gp0 = Gperm + ((long)blk*16 + w)*256 + (long)u*4 + quad;
  ushort_t gb[4];
  #pragma unroll
  for (int g = 0; g < 4; g++) gb[g] = gp0[(long)T0*131072 + g*64];

  for (int t = T0; t < T1; t++){
    #pragma unroll
    for (int g = 0; g < 4; g++) acc[g][0] = bf2f(gb[g]);
    // lgkm-only barrier: h8 write(t-1) -> read(t) edge; vbf store + Gperm loads
    // stay in flight across the barrier (T4: never drain vmcnt in the loop).
    asm volatile("s_waitcnt lgkmcnt(0)\n\ts_barrier" ::: "memory");
    intx8 af0 = *(const intx8*)(const void*)&h8[t & 1][u][quad*32];
    intx8 af1 = *(const intx8*)(const void*)&h8[t & 1][u][128 + quad*32];
    // EARLY: coalesced vbf dump of h(t-1) (independent of MFMAs; VMEM pipe)
    if (t && w < 4){
      ushort_t* vrow = vbf + ((long)(t-1) * B_ + blk*4 + w) * 768;
      uint32 p = *(const uint32*)(const void*)&h8[t & 1][4*w][lane*4];
      float2v lo = __builtin_amdgcn_cvt_pk_f32_fp8(p, false);
      float2v hi = __builtin_amdgcn_cvt_pk_f32_fp8(p, true);
      short4v pk;
      pk[0] = (short)f2bf(lo[0]); pk[1] = (short)f2bf(lo[1]);
      pk[2] = (short)f2bf(hi[0]); pk[3] = (short)f2bf(hi[1]);
      *(short4v*)(void*)&vrow[lane*4] = pk;
    }
    // EARLY: prefetch next Gperm values (hides HBM latency under MFMAs)
    if (t + 1 < T_){
      const ushort_t* gp = gp0 + (long)(t+1)*131072;
      #pragma unroll
      for (int g = 0; g < 4; g++) gb[g] = gp[g*64];
    }
    // gates i,f
    acc[0] = __builtin_amdgcn_mfma_scale_f32_16x16x128_f8f6f4(
        af0, wfx[0][0], acc[0], 0, 0, 0, 0x7F7F7F7F, 0, 0x7F7F7F7F);
    acc[0] = __builtin_amdgcn_mfma_scale_f32_16x16x128_f8f6f4(
        af1, wfx[0][1], acc[0], 0, 0, 0, 0x7F7F7F7F, 0, 0x7F7F7F7F);
    acc[1] = __builtin_amdgcn_mfma_scale_f32_16x16x128_f8f6f4(
        af0, wfx[1][0], acc[1], 0, 0, 0, 0x7F7F7F7F, 0, 0x7F7F7F7F);
    acc[1] = __builtin_amdgcn_mfma_scale_f32_16x16x128_f8f6f4(
        af1, wfx[1][1], acc[1], 0, 0, 0, 0x7F7F7F7F, 0, 0x7F7F7F7F);
    // i,f activations co-issue on VALU while g,o MFMAs occupy the matrix pipe
    float iv = fsig (acc[0][0]);
    float fv = fsig (acc[1][0]);
    // gates g,o
    acc[2] = __builtin_amdgcn_mfma_scale_f32_16x16x128_f8f6f4(
        af0, wfx[2][0], acc[2], 0, 0, 0, 0x7F7F7F7F, 0, 0x7F7F7F7F);
    acc[2] = __builtin_amdgcn_mfma_scale_f32_16x16x128_f8f6f4(
        af1, wfx[2][1], acc[2], 0, 0, 0, 0x7F7F7F7F, 0, 0x7F7F7F7F);
    acc[3] = __builtin_amdgcn_mfma_scale_f32_16x16x128_f8f6f4(
        af0, wfx[3][0], acc[3], 0, 0, 0, 0x7F7F7F7F, 0, 0x7F7F7F7F);
    acc[3] = __builtin_amdgcn_mfma_scale_f32_16x16x128_f8f6f4(
        af1, wfx[3][1], acc[3], 0, 0, 0, 0x7F7F7F7F, 0, 0x7F7F7F7F);
    float gv = ftanh(acc[2][0]);
    float ov = fsig (acc[3][0]);
    float c  = fv * c_reg + iv * gv;
    c_reg = c;
    float h  = ov * ftanh(c);
    int p8 = __builtin_amdgcn_cvt_pk_fp8_f32(h, h, 0, false);
    h8[(t+1)&1][quad*4][w*16 + u] = (char)(p8 & 0xff);
  }
  __syncthreads();
  if (PHASE == 0){
    // h(255) sits in h8[0]; save real rows + per-thread c for phase 1
    if (w < 4)
      ((uint32*)(hsave + (blk*4 + w)*256))[lane] = *(const uint32*)&h8[0][4*w][lane*4];
    csave[((blk*16 + w) << 6) + lane] = c_reg;
  } else {
    // final dump: h(511) lives in h8[0]
    if (w < 4){
      ushort_t* vrow = vbf + ((long)(T_-1) * B_ + blk*4 + w) * 768;
      uint32 p = *(const uint32*)(const void*)&h8[0][4*w][lane*4];
      float2v lo = __builtin_amdgcn_cvt_pk_f32_fp8(p, false);
      float2v hi = __builtin_amdgcn_cvt_pk_f32_fp8(p, true);
      short4v pk;
      pk[0] = (short)f2bf(lo[0]); pk[1] = (short)f2bf(lo[1]);
      pk[2] = (short)f2bf(hi[0]); pk[3] = (short)f2bf(hi[1]);
      *(short4v*)(void*)&vrow[lane*4] = pk;
    }
  }
}

extern "C" void kernel_launch(void* const* d_in, const int* in_sizes, int n_in,
                              void* d_out, int out_size, void* d_ws, size_t ws_size,
                              hipStream_t stream){
  (void)in_sizes; (void)n_in; (void)out_size; (void)ws_size;
  const float* enc     = (const float*)d_in[0];
  const int*   sep     = (const int*)  d_in[1];
  const int*   pos_ids = (const int*)  d_in[2];
  const int*   len     = (const int*)  d_in[3];
  const float* pos_emb = (const float*)d_in[4];
  const float* wl_emb  = (const float*)d_in[5];
  const float* fcW     = (const float*)d_in[6];
  const float* fcb     = (const float*)d_in[7];
  const float* W_ih    = (const float*)d_in[8];
  const float* W_hh    = (const float*)d_in[9];
  const float* b_ih    = (const float*)d_in[10];
  const float* b_hh    = (const float*)d_in[11];
  const float* combW   = (const float*)d_in[12];

  char* ws = (char*)d_ws;
  int*      ls    = (int*)     (ws + OFF_LS);
  int*      lp    = (int*)     (ws + OFF_LP);
  int*      wid   = (int*)     (ws + OFF_WID);
  float*    inv   = (float*)   (ws + OFF_INV);
  float*    csave = (float*)   (ws + OFF_CSAVE);
  char*     hsave = (char*)    (ws + OFF_HSAVE);
  float*    posW  = (float*)   (ws + OFF_POSW);
  float*    wlW   = (float*)   (ws + OFF_WLW);
  float*    biasg = (float*)   (ws + OFF_BIASG);
  char*     whh8  = (char*)    (ws + OFF_WHH);
  ushort_t* wih   = (ushort_t*)(ws + OFF_WIH);
  ushort_t* wenc  = (ushort_t*)(ws + OFF_WENC);
  ushort_t* combwb= (ushort_t*)(ws + OFF_COMBW);
  ushort_t* ecw   = (ushort_t*)(ws + OFF_ECW);
  ushort_t* zbf   = (ushort_t*)(ws + OFF_Z);
  ushort_t* gperm = (ushort_t*)(ws + OFF_GPERM);
  ushort_t* vbf   = (ushort_t*)(ws + OFF_VBF);

  k_scan<<<B_, 512, 0, stream>>>(sep, pos_ids, ls, lp, wid, inv);
  k_encbf<<<2048, 256, 0, stream>>>(enc, vbf);
  k_small<<<2530, 256, 0, stream>>>(pos_emb, wl_emb, fcW, W_ih, W_hh, b_ih, b_hh, combW,
                                    posW, wlW, biasg, whh8, wih, wenc, combwb);
  // E = enc @ Wenc^T  (128x256 dbuf tile; N=200 in one 256 tile)
  k_big<0><<<dim3(1, BT_/128), 512, 0, stream>>>(vbf + 256, 768L, wenc, 512, LIN_, ecw, nullptr);
  // exclusive cumsum over t (in place) -> CW
  k_cum200<<<B_, 256, 0, stream>>>(ecw);
  // z = tanh(...) (8 rows per block)
  k_z<<<BT_/8, 256, 0, stream>>>(ecw, ls, lp, wid, inv, posW, wlW, fcb, zbf);
  // Gperm = z @ W_ih^T + biases (128x256 dbuf tile, Gperm-swizzled epilogue)
  k_big<1><<<dim3(4, BT_/128), 512, 0, stream>>>(zbf, (long)LINP_, wih, LINP_, G4_, gperm, biasg);
  // LSTM recurrence, two 256-step phases (c/h handoff via csave/hsave)
  k_rec2<0><<<32, 1024, 0, stream>>>(gperm, whh8, vbf, csave, hsave);
  k_rec2<1><<<32, 1024, 0, stream>>>(gperm, whh8, vbf, csave, hsave);
  // logits = [hs, enc] @ combine_W^T (256x64 dbuf tile), masked, b-major output
  k_logit<<<BT_/256, 512, 0, stream>>>(vbf, combwb, (float*)d_out, len);
}

// Round 11
// 819.285 us; speedup vs baseline: 1.0373x; 1.0373x over previous
//
#include <hip/hip_runtime.h>

typedef unsigned short ushort_t;
typedef unsigned int uint32;
typedef __attribute__((ext_vector_type(8))) short short8;
typedef __attribute__((ext_vector_type(4))) short short4v;
typedef __attribute__((ext_vector_type(4))) float floatx4;
typedef __attribute__((ext_vector_type(2))) float float2v;
typedef __attribute__((ext_vector_type(8))) int intx8;

#define B_    128
#define T_    512
#define H_    256
#define H2_   512
#define LIN_  200
#define LINP_ 224
#define G4_   1024
#define SP_   58
#define BT_   (B_*T_)

// ---------- ws layout (bytes) ----------
#define OFF_LS     0UL          // int  [B,T]      262144
#define OFF_LP     262144UL     // int  [B,T]      262144
#define OFF_WID    524288UL     // int  [B,T]      262144
#define OFF_INV    786432UL     // f32  [B,T]      262144
#define OFF_POSW   1212416UL    // f32  [32][200]   25600
#define OFF_WLW    1238016UL    // f32  [8][200]     6400
#define OFF_BIASG  1244416UL    // f32  [1024]       4096
#define OFF_WHH    1248512UL    // fp8  [1024][256] 262144
#define OFF_WIH    1772800UL    // bf16 [1024][224] 458752
#define OFF_WENC   2231552UL    // bf16 [200][512]  204800
#define OFF_COMBW  2436352UL    // bf16 [58][768]    89088
#define OFF_ECW    2525440UL    // bf16 [65536][200] time-major rows (t*128+b)
#define OFF_Z      28739840UL   // bf16 [65536][224] time-major rows
#define OFF_GPERM  58099968UL   // bf16 swizzled [512][32 blk][16 w][4 g][16 u][4 qd]
#define OFF_VBF    192317696UL  // bf16 [65536][768] time-major rows (0:256 hs, 256:768 enc)

__device__ __forceinline__ ushort_t f2bf(float x){
  uint32 u = __float_as_uint(x);
  u += 0x7fffu + ((u >> 16) & 1u);
  return (ushort_t)(u >> 16);
}
__device__ __forceinline__ float bf2f(ushort_t v){
  return __uint_as_float(((uint32)v) << 16);
}
// fast sigmoid/tanh (exp2-based __expf + v_rcp); |err| ~1e-5, way inside bf16
__device__ __forceinline__ float fsig(float x){
  return __builtin_amdgcn_rcpf(1.0f + __expf(-x));
}
__device__ __forceinline__ float ftanh(float x){
  return 1.0f - 2.0f * __builtin_amdgcn_rcpf(1.0f + __expf(2.0f * x));
}

// ---------- scan: last_sep / wordlen / last_pos, parallel Hillis-Steele ----------
__global__ __launch_bounds__(512) void k_scan(const int* __restrict__ sep, const int* __restrict__ pos_ids,
                       int* __restrict__ ls, int* __restrict__ lp,
                       int* __restrict__ wid, float* __restrict__ inv){
  int b = blockIdx.x, t = threadIdx.x;
  __shared__ int sm[512];
  int v = (sep[b*T_ + t] > 0) ? t : 0;
  sm[t] = v;
  __syncthreads();
  #pragma unroll
  for (int off = 1; off < 512; off <<= 1){
    int o = (t >= off) ? sm[t - off] : 0;
    __syncthreads();
    v = (o > v) ? o : v;
    sm[t] = v;
    __syncthreads();
  }
  int l = (t == 0) ? 0 : sm[t - 1];      // last sep strictly before t
  int wlen = t - l;
  int wsv  = (wlen < 1) ? 1 : wlen;
  ls[b*T_ + t]  = l;
  lp[b*T_ + t]  = pos_ids[b*T_ + l];
  wid[b*T_ + t] = (wsv > 7) ? 7 : wsv;
  inv[b*T_ + t] = 1.0f / (float)wsv;
}

// ---------- enc -> bf16 into vbf[t*128+b][256:768] ----------
__global__ __launch_bounds__(256) void k_encbf(const float* __restrict__ enc, ushort_t* __restrict__ vbf){
  const long total = (long)BT_ * 128;          // float4 count (65536 rows x 128)
  for (long i = (long)blockIdx.x * 256 + threadIdx.x; i < total; i += 2048L * 256){
    floatx4 v = ((const floatx4*)enc)[i];
    long row = i >> 7;                         // b*512 + t (enc layout)
    int c4 = (int)(i & 127);
    int b = (int)(row >> 9), t = (int)(row & (T_-1));
    short4v pk;
    pk[0] = (short)f2bf(v[0]); pk[1] = (short)f2bf(v[1]);
    pk[2] = (short)f2bf(v[2]); pk[3] = (short)f2bf(v[3]);
    *(short4v*)(void*)(vbf + ((long)t * B_ + b) * 768 + 256 + c4*4) = pk;
  }
}

// ---------- small precomputes / weight conversions ----------
__global__ __launch_bounds__(256) void k_small(
    const float* __restrict__ pos_emb, const float* __restrict__ wl_emb,
    const float* __restrict__ fcW, const float* __restrict__ W_ih,
    const float* __restrict__ W_hh, const float* __restrict__ b_ih,
    const float* __restrict__ b_hh, const float* __restrict__ combW,
    float* __restrict__ posW, float* __restrict__ wlW, float* __restrict__ biasg,
    char* __restrict__ whh8, ushort_t* __restrict__ wih,
    ushort_t* __restrict__ wenc, ushort_t* __restrict__ combwb){
  int idx = blockIdx.x * 256 + threadIdx.x;
  if (idx < 6400){
    int p = idx / 200, l = idx % 200;
    float s = 0.f;
    for (int d = 0; d < 50; d++) s += pos_emb[p*50 + d] * fcW[l*582 + d];
    posW[idx] = s; return;
  }
  idx -= 6400;
  if (idx < 1600){
    int w = idx / 200, l = idx % 200;
    float s = 0.f;
    for (int d = 0; d < 20; d++) s += wl_emb[w*20 + d] * fcW[l*582 + 562 + d];
    wlW[idx] = s; return;
  }
  idx -= 1600;
  if (idx < 1024){ biasg[idx] = b_ih[idx] + b_hh[idx]; return; }
  idx -= 1024;
  if (idx < 262144){
    int p8 = __builtin_amdgcn_cvt_pk_fp8_f32(W_hh[idx], W_hh[idx], 0, false);
    whh8[idx] = (char)(p8 & 0xff);
    return;
  }
  idx -= 262144;
  if (idx < 229376){
    int n = idx / 224, k = idx % 224;
    wih[idx] = (k < 200) ? f2bf(W_ih[n*200 + k]) : (ushort_t)0;
    return;
  }
  idx -= 229376;
  if (idx < 102400){
    int l = idx / 512, c = idx % 512;
    wenc[idx] = f2bf(fcW[l*582 + 50 + c]); return;
  }
  idx -= 102400;
  if (idx < 44544){ combwb[idx] = f2bf(combW[idx]); return; }
}

// ---------- 128x256 8-wave double-buffered bf16 GEMM (mid GEMMs, short K) ----------
// One vmcnt(0)+barrier per K-step, prefetch issued before compute (T3-minimal).
// Linear LDS (gload_lds dst) + XOR swizzle byte^=((row>>1)&3)<<4 applied BOTH sides
// (pre-swizzled source granule + swizzled read addr, rule #21). Harness-verified r9.
template<int EPI>
__global__ __launch_bounds__(512, 2) void k_big(
    const ushort_t* __restrict__ A, long lda,
    const ushort_t* __restrict__ Bm, int K, int Nvalid,
    void* __restrict__ Cout, const float* __restrict__ bias){
  __shared__ __attribute__((aligned(16))) ushort_t As[2][128][32];
  __shared__ __attribute__((aligned(16))) ushort_t Bs[2][256][32];
  int tid  = threadIdx.x;
  int lane = tid & 63, w = tid >> 6;          // 8 waves
  int u = lane & 15, quad = lane >> 4;
  int wm = w >> 2, wn = w & 3;                // 2x4 wave grid, 64x64 per wave
  long m0 = (long)blockIdx.y * 128;
  int  n0 = blockIdx.x * 256;
  int sr = lane >> 2;
  int gp = lane & 3;
  int gl = gp ^ ((sr >> 1) & 3);              // logical granule this lane fetches
  int arow = w*16 + sr;
  const ushort_t* asrc = A + (m0 + arow) * lda + gl*8;
  int brow = w*32 + sr;
  const ushort_t* bsrc0 = Bm + (long)(n0 + brow) * K + gl*8;
  const ushort_t* bsrc1 = Bm + (long)(n0 + brow + 16) * K + gl*8;
  floatx4 acc[4][4] = {};

#define STAGEK(buf, kk) do{ \
    __builtin_amdgcn_global_load_lds( \
        (const __attribute__((address_space(1))) void*)(asrc + (kk)), \
        (__attribute__((address_space(3))) void*)((char*)&As[buf][0][0] + w*1024), 16, 0, 0); \
    __builtin_amdgcn_global_load_lds( \
        (const __attribute__((address_space(1))) void*)(bsrc0 + (kk)), \
        (__attribute__((address_space(3))) void*)((char*)&Bs[buf][0][0] + w*2048), 16, 0, 0); \
    __builtin_amdgcn_global_load_lds( \
        (const __attribute__((address_space(1))) void*)(bsrc1 + (kk)), \
        (__attribute__((address_space(3))) void*)((char*)&Bs[buf][0][0] + w*2048 + 1024), 16, 0, 0); \
  }while(0)

  STAGEK(0, 0);
  asm volatile("s_waitcnt vmcnt(0)\n\ts_barrier" ::: "memory");
  int nk = K >> 5;
  int cur = 0;
  for (int ks = 0; ks < nk; ks++){
    if (ks + 1 < nk) STAGEK(cur ^ 1, (ks + 1) << 5);
    short8 af[4], bfv[4];
    #pragma unroll
    for (int mi = 0; mi < 4; mi++){
      int row = wm*64 + mi*16 + u;
      int off = (row*64 + quad*16) ^ (((row >> 1) & 3) << 4);
      af[mi] = *(const short8*)(const void*)((const char*)&As[cur][0][0] + off);
    }
    #pragma unroll
    for (int ni = 0; ni < 4; ni++){
      int row = wn*64 + ni*16 + u;
      int off = (row*64 + quad*16) ^ (((row >> 1) & 3) << 4);
      bfv[ni] = *(const short8*)(const void*)((const char*)&Bs[cur][0][0] + off);
    }
    #pragma unroll
    for (int mi = 0; mi < 4; mi++)
      #pragma unroll
      for (int ni = 0; ni < 4; ni++)
        acc[mi][ni] = __builtin_amdgcn_mfma_f32_16x16x32_bf16(af[mi], bfv[ni], acc[mi][ni], 0, 0, 0);
    asm volatile("s_waitcnt vmcnt(0)\n\ts_barrier" ::: "memory");
    cur ^= 1;
  }
#undef STAGEK

  if (EPI == 1){
    #pragma unroll
    for (int mi = 0; mi < 4; mi++){
      #pragma unroll
      for (int ni = 0; ni < 4; ni++){
        long mm = m0 + wm*64 + mi*16 + quad*4;   // 4 r's = 4 consecutive b (qd 0..3)
        int n = n0 + wn*64 + ni*16 + u;
        float bv = bias[n];
        int t = (int)(mm >> 7);
        int b = (int)(mm & 127);
        int blk = b >> 2;                         // b % 4 == 0 here
        int g = n >> 8, j = n & 255, ut = j & 15, jt = j >> 4;
        long idx = ((((long)t*32 + blk)*16 + jt)*4 + g)*64 + ut*4;
        short4v pk;
        #pragma unroll
        for (int r = 0; r < 4; r++) pk[r] = (short)f2bf(acc[mi][ni][r] + bv);
        *(short4v*)(void*)((ushort_t*)Cout + idx) = pk;
      }
    }
  } else {
    for (int mi = 0; mi < 4; mi++){
      for (int ni = 0; ni < 4; ni++){
        int n = n0 + wn*64 + ni*16 + u;
        if (n < Nvalid){
          #pragma unroll
          for (int r = 0; r < 4; r++){
            long m = m0 + wm*64 + mi*16 + quad*4 + r;
            ((ushort_t*)Cout)[m * Nvalid + n] = f2bf(acc[mi][ni][r]);
          }
        }
      }
    }
  }
}

// ---------- logits GEMM: BM=256 x BN=64, 8 waves (4x2), dbuf + gload_lds ----------
__global__ __launch_bounds__(512, 2) void k_logit(
    const ushort_t* __restrict__ A,          // vbf [65536][768]
    const ushort_t* __restrict__ Bm,         // combwb [58][768]
    float* __restrict__ Cout, const int* __restrict__ len){
  __shared__ __attribute__((aligned(16))) ushort_t As[2][256][32];
  __shared__ __attribute__((aligned(16))) ushort_t Bs[2][64][32];
  int tid  = threadIdx.x;
  int lane = tid & 63, w = tid >> 6;          // 8 waves
  int u = lane & 15, quad = lane >> 4;
  int wm = w >> 1, wn = w & 1;                // 4x2 wave grid, 64x32 per wave
  long m0 = (long)blockIdx.x * 256;
  int sr = lane >> 2;
  int gp = lane & 3;
  int gl = gp ^ ((sr >> 1) & 3);
  const ushort_t* asrc0 = A + (m0 + w*32 + sr) * 768 + gl*8;
  const ushort_t* asrc1 = A + (m0 + w*32 + 16 + sr) * 768 + gl*8;
  const ushort_t* bsrc  = Bm + (long)(w*16 + sr) * 768 + gl*8;   // waves 0..3 only
  floatx4 acc[4][2] = {};

#define STG(buf, kk) do{ \
    __builtin_amdgcn_global_load_lds( \
        (const __attribute__((address_space(1))) void*)(asrc0 + (kk)), \
        (__attribute__((address_space(3))) void*)((char*)&As[buf][0][0] + w*2048), 16, 0, 0); \
    __builtin_amdgcn_global_load_lds( \
        (const __attribute__((address_space(1))) void*)(asrc1 + (kk)), \
        (__attribute__((address_space(3))) void*)((char*)&As[buf][0][0] + w*2048 + 1024), 16, 0, 0); \
    if (w < 4) __builtin_amdgcn_global_load_lds( \
        (const __attribute__((address_space(1))) void*)(bsrc + (kk)), \
        (__attribute__((address_space(3))) void*)((char*)&Bs[buf][0][0] + w*1024), 16, 0, 0); \
  }while(0)

  STG(0, 0);
  asm volatile("s_waitcnt vmcnt(0)\n\ts_barrier" ::: "memory");
  int cur = 0;
  for (int ks = 0; ks < 24; ks++){
    if (ks + 1 < 24) STG(cur ^ 1, (ks + 1) << 5);
    short8 af[4], bfv[2];
    #pragma unroll
    for (int mi = 0; mi < 4; mi++){
      int row = wm*64 + mi*16 + u;
      int off = (row*64 + quad*16) ^ (((row >> 1) & 3) << 4);
      af[mi] = *(const short8*)(const void*)((const char*)&As[cur][0][0] + off);
    }
    #pragma unroll
    for (int ni = 0; ni < 2; ni++){
      int row = wn*32 + ni*16 + u;
      int off = (row*64 + quad*16) ^ (((row >> 1) & 3) << 4);
      bfv[ni] = *(const short8*)(const void*)((const char*)&Bs[cur][0][0] + off);
    }
    #pragma unroll
    for (int mi = 0; mi < 4; mi++)
      #pragma unroll
      for (int ni = 0; ni < 2; ni++)
        acc[mi][ni] = __builtin_amdgcn_mfma_f32_16x16x32_bf16(af[mi], bfv[ni], acc[mi][ni], 0, 0, 0);
    asm volatile("s_waitcnt vmcnt(0)\n\ts_barrier" ::: "memory");
    cur ^= 1;
  }
#undef STG

  #pragma unroll
  for (int mi = 0; mi < 4; mi++){
    #pragma unroll
    for (int ni = 0; ni < 2; ni++){
      int n = wn*32 + ni*16 + u;
      if (n < SP_){
        #pragma unroll
        for (int r = 0; r < 4; r++){
          long m = m0 + wm*64 + mi*16 + quad*4 + r;
          int t = (int)(m >> 7); int b = (int)(m & 127);
          float o = (t < len[b]) ? acc[mi][ni][r] : 0.0f;
          if (t == 0 && n == 0) o = -1e30f;
          Cout[((long)b * T_ + t) * SP_ + n] = o;
        }
      }
    }
  }
}

// ---------- exclusive cumsum over t, in place on E (bf16, time-major rows) ----------
__global__ __launch_bounds__(256) void k_cum200(ushort_t* __restrict__ E){
  int b = blockIdx.x;
  int c = threadIdx.x;
  if (c >= LIN_) return;
  float acc = 0.f;
  ushort_t* p = E + (long)b * LIN_ + c;      // row (t*128+b)
  const long rs = (long)B_ * LIN_;           // per-t stride
  for (int t0 = 0; t0 < T_; t0 += 16){
    float vv[16];
    #pragma unroll
    for (int i = 0; i < 16; i++) vv[i] = bf2f(p[i*rs]);
    #pragma unroll
    for (int i = 0; i < 16; i++){ p[i*rs] = f2bf(acc); acc += vv[i]; }
    p += 16*rs;
  }
}

// ---------- z = tanh((CW[t]-CW[ls])*inv + posW + wlW + b), t=0 -> 0, pad K to 224 ----------
__global__ __launch_bounds__(256) void k_z(
    const ushort_t* __restrict__ CW, const int* __restrict__ ls, const int* __restrict__ lp,
    const int* __restrict__ wid, const float* __restrict__ inv,
    const float* __restrict__ posW, const float* __restrict__ wlW,
    const float* __restrict__ fcb, ushort_t* __restrict__ zbf){
  int l = threadIdx.x;
  if (l >= LINP_) return;
  float fb = (l < LIN_) ? fcb[l] : 0.f;
  #pragma unroll
  for (int i = 0; i < 8; i++){
    int m = blockIdx.x * 8 + i;       // time-major row t*128+b
    int t = m >> 7;
    int b = m & 127;
    int ar = b * T_ + t;              // b-major aux index
    ushort_t o = 0;
    if (t != 0 && l < LIN_){
      int lsv = ls[ar];
      float x = bf2f(CW[(long)m * LIN_ + l]) - bf2f(CW[((long)lsv * B_ + b) * LIN_ + l]);
      x = x * inv[ar] + posW[lp[ar]*LIN_ + l] + wlW[wid[ar]*LIN_ + l] + fb;
      o = f2bf(ftanh(x));
    }
    zbf[(long)m * LINP_ + l] = o;
  }
}

// ---------- LSTM recurrence: 32 blocks x 1024 threads, NB=4 batches/block ----------
// Round-5/7 plateau form (438us). SPLIT REVERTED: two 256-step halves cost +33us
// (launch-gap/drain/warm-up), and the top-5 instrumentation goal failed (window is
// global across iterations, both halves still fill it). Per-step budget = 1104cyc
// MFMA issue (decomposition-invariant, verified over NB/blocks/waves variants) +
// ~950cyc serial h-dependency chain (barrier->ds_read->MFMA->activations->ds_write);
// scheduling levers (setprio, dump ring, packed h4, interleave beyond current) all
// measured neutral. Structural plateau for the per-step-barrier LSTM decomposition.
__global__ __launch_bounds__(1024, 4) void k_rec(
    const ushort_t* __restrict__ Gperm, const char* __restrict__ whh8,
    ushort_t* __restrict__ vbf){
  int blk  = blockIdx.x;                      // 0..31: batches blk*4 .. blk*4+3
  int tid  = threadIdx.x;
  int lane = tid & 63, w = tid >> 6;          // w in [0,16): hidden j-tile
  int u = lane & 15, quad = lane >> 4;        // quad = local batch index
  __shared__ __attribute__((aligned(16))) char h8[2][16][272];   // row stride 272
  for (int i = tid; i < (int)(sizeof(h8)/4); i += 1024) ((int*)h8)[i] = 0;

  // W_hh fp8 B-fragments (MX K=128): gate g, cols w*16+u; pinned in VGPRs.
  intx8 wfx[4][2];
  #pragma unroll
  for (int g = 0; g < 4; g++){
    int grow = g*256 + w*16 + u;
    #pragma unroll
    for (int kc = 0; kc < 2; kc++){
      intx8 v = *(const intx8*)(const void*)(whh8 + (long)grow*256 + kc*128 + quad*32);
      asm volatile("" : "+v"(v));
      wfx[g][kc] = v;
    }
  }
  float c_reg = 0.f;
  floatx4 acc[4] = {};   // element 0 rebuilt each step; elements 1..3 stay 0 forever

  // Gperm[t][blk][w][g][u][qd]: lane (quad,u) reads gate g at g*64 + u*4 + quad
  const ushort_t* gp0 = Gperm + ((long)blk*16 + w)*256 + (long)u*4 + quad;
  ushort_t gb[4];
  #pragma unroll
  for (int g = 0; g < 4; g++) gb[g] = gp0[g*64];

  for (int t = 0; t < T_; t++){
    #pragma unroll
    for (int g = 0; g < 4; g++) acc[g][0] = bf2f(gb[g]);
    // lgkm-only barrier: h8 write(t-1) -> read(t) edge; vbf store + Gperm loads
    // stay in flight across the barrier (T4: never drain vmcnt in the loop).
    asm volatile("s_waitcnt lgkmcnt(0)\n\ts_barrier" ::: "memory");
    intx8 af0 = *(const intx8*)(const void*)&h8[t & 1][u][quad*32];
    intx8 af1 = *(const intx8*)(const void*)&h8[t & 1][u][128 + quad*32];
    // EARLY: coalesced vbf dump of h(t-1) (independent of MFMAs; VMEM pipe)
    if (t && w < 4){
      ushort_t* vrow = vbf + ((long)(t-1) * B_ + blk*4 + w) * 768;
      uint32 p = *(const uint32*)(const void*)&h8[t & 1][4*w][lane*4];
      float2v lo = __builtin_amdgcn_cvt_pk_f32_fp8(p, false);
      float2v hi = __builtin_amdgcn_cvt_pk_f32_fp8(p, true);
      short4v pk;
      pk[0] = (short)f2bf(lo[0]); pk[1] = (short)f2bf(lo[1]);
      pk[2] = (short)f2bf(hi[0]); pk[3] = (short)f2bf(hi[1]);
      *(short4v*)(void*)&vrow[lane*4] = pk;
    }
    // EARLY: prefetch next Gperm values (hides HBM latency under MFMAs)
    if (t + 1 < T_){
      const ushort_t* gp = gp0 + (long)(t+1)*131072;
      #pragma unroll
      for (int g = 0; g < 4; g++) gb[g] = gp[g*64];
    }
    // gates i,f
    acc[0] = __builtin_amdgcn_mfma_scale_f32_16x16x128_f8f6f4(
        af0, wfx[0][0], acc[0], 0, 0, 0, 0x7F7F7F7F, 0, 0x7F7F7F7F);
    acc[0] = __builtin_amdgcn_mfma_scale_f32_16x16x128_f8f6f4(
        af1, wfx[0][1], acc[0], 0, 0, 0, 0x7F7F7F7F, 0, 0x7F7F7F7F);
    acc[1] = __builtin_amdgcn_mfma_scale_f32_16x16x128_f8f6f4(
        af0, wfx[1][0], acc[1], 0, 0, 0, 0x7F7F7F7F, 0, 0x7F7F7F7F);
    acc[1] = __builtin_amdgcn_mfma_scale_f32_16x16x128_f8f6f4(
        af1, wfx[1][1], acc[1], 0, 0, 0, 0x7F7F7F7F, 0, 0x7F7F7F7F);
    // i,f activations co-issue on VALU while g,o MFMAs occupy the matrix pipe
    float iv = fsig (acc[0][0]);
    float fv = fsig (acc[1][0]);
    // gates g,o
    acc[2] = __builtin_amdgcn_mfma_scale_f32_16x16x128_f8f6f4(
        af0, wfx[2][0], acc[2], 0, 0, 0, 0x7F7F7F7F, 0, 0x7F7F7F7F);
    acc[2] = __builtin_amdgcn_mfma_scale_f32_16x16x128_f8f6f4(
        af1, wfx[2][1], acc[2], 0, 0, 0, 0x7F7F7F7F, 0, 0x7F7F7F7F);
    acc[3] = __builtin_amdgcn_mfma_scale_f32_16x16x128_f8f6f4(
        af0, wfx[3][0], acc[3], 0, 0, 0, 0x7F7F7F7F, 0, 0x7F7F7F7F);
    acc[3] = __builtin_amdgcn_mfma_scale_f32_16x16x128_f8f6f4(
        af1, wfx[3][1], acc[3], 0, 0, 0, 0x7F7F7F7F, 0, 0x7F7F7F7F);
    float gv = ftanh(acc[2][0]);
    float ov = fsig (acc[3][0]);
    float c  = fv * c_reg + iv * gv;
    c_reg = c;
    float h  = ov * ftanh(c);
    int p8 = __builtin_amdgcn_cvt_pk_fp8_f32(h, h, 0, false);
    h8[(t+1)&1][quad*4][w*16 + u] = (char)(p8 & 0xff);
  }
  __syncthreads();
  // final dump: h(511) lives in h8[0]
  if (w < 4){
    ushort_t* vrow = vbf + ((long)(T_-1) * B_ + blk*4 + w) * 768;
    uint32 p = *(const uint32*)(const void*)&h8[0][4*w][lane*4];
    float2v lo = __builtin_amdgcn_cvt_pk_f32_fp8(p, false);
    float2v hi = __builtin_amdgcn_cvt_pk_f32_fp8(p, true);
    short4v pk;
    pk[0] = (short)f2bf(lo[0]); pk[1] = (short)f2bf(lo[1]);
    pk[2] = (short)f2bf(hi[0]); pk[3] = (short)f2bf(hi[1]);
    *(short4v*)(void*)&vrow[lane*4] = pk;
  }
}

extern "C" void kernel_launch(void* const* d_in, const int* in_sizes, int n_in,
                              void* d_out, int out_size, void* d_ws, size_t ws_size,
                              hipStream_t stream){
  (void)in_sizes; (void)n_in; (void)out_size; (void)ws_size;
  const float* enc     = (const float*)d_in[0];
  const int*   sep     = (const int*)  d_in[1];
  const int*   pos_ids = (const int*)  d_in[2];
  const int*   len     = (const int*)  d_in[3];
  const float* pos_emb = (const float*)d_in[4];
  const float* wl_emb  = (const float*)d_in[5];
  const float* fcW     = (const float*)d_in[6];
  const float* fcb     = (const float*)d_in[7];
  const float* W_ih    = (const float*)d_in[8];
  const float* W_hh    = (const float*)d_in[9];
  const float* b_ih    = (const float*)d_in[10];
  const float* b_hh    = (const float*)d_in[11];
  const float* combW   = (const float*)d_in[12];

  char* ws = (char*)d_ws;
  int*      ls    = (int*)     (ws + OFF_LS);
  int*      lp    = (int*)     (ws + OFF_LP);
  int*      wid   = (int*)     (ws + OFF_WID);
  float*    inv   = (float*)   (ws + OFF_INV);
  float*    posW  = (float*)   (ws + OFF_POSW);
  float*    wlW   = (float*)   (ws + OFF_WLW);
  float*    biasg = (float*)   (ws + OFF_BIASG);
  char*     whh8  = (char*)    (ws + OFF_WHH);
  ushort_t* wih   = (ushort_t*)(ws + OFF_WIH);
  ushort_t* wenc  = (ushort_t*)(ws + OFF_WENC);
  ushort_t* combwb= (ushort_t*)(ws + OFF_COMBW);
  ushort_t* ecw   = (ushort_t*)(ws + OFF_ECW);
  ushort_t* zbf   = (ushort_t*)(ws + OFF_Z);
  ushort_t* gperm = (ushort_t*)(ws + OFF_GPERM);
  ushort_t* vbf   = (ushort_t*)(ws + OFF_VBF);

  k_scan<<<B_, 512, 0, stream>>>(sep, pos_ids, ls, lp, wid, inv);
  k_encbf<<<2048, 256, 0, stream>>>(enc, vbf);
  k_small<<<2530, 256, 0, stream>>>(pos_emb, wl_emb, fcW, W_ih, W_hh, b_ih, b_hh, combW,
                                    posW, wlW, biasg, whh8, wih, wenc, combwb);
  // E = enc @ Wenc^T  (128x256 dbuf tile; N=200 in one 256 tile)
  k_big<0><<<dim3(1, BT_/128), 512, 0, stream>>>(vbf + 256, 768L, wenc, 512, LIN_, ecw, nullptr);
  // exclusive cumsum over t (in place) -> CW
  k_cum200<<<B_, 256, 0, stream>>>(ecw);
  // z = tanh(...) (8 rows per block)
  k_z<<<BT_/8, 256, 0, stream>>>(ecw, ls, lp, wid, inv, posW, wlW, fcb, zbf);
  // Gperm = z @ W_ih^T + biases (128x256 dbuf tile, Gperm-swizzled epilogue)
  k_big<1><<<dim3(4, BT_/128), 512, 0, stream>>>(zbf, (long)LINP_, wih, LINP_, G4_, gperm, biasg);
  // LSTM recurrence (single kernel, round-5/7 plateau form)
  k_rec<<<32, 1024, 0, stream>>>(gperm, whh8, vbf);
  // logits = [hs, enc] @ combine_W^T (256x64 dbuf tile), masked, b-major output
  k_logit<<<BT_/256, 512, 0, stream>>>(vbf, combwb, (float*)d_out, len);
}

// Round 12
// 809.558 us; speedup vs baseline: 1.0497x; 1.0120x over previous
//
#include <hip/hip_runtime.h>

typedef unsigned short ushort_t;
typedef unsigned int uint32;
typedef __attribute__((ext_vector_type(8))) short short8;
typedef __attribute__((ext_vector_type(4))) short short4v;
typedef __attribute__((ext_vector_type(4))) float floatx4;
typedef __attribute__((ext_vector_type(2))) float float2v;
typedef __attribute__((ext_vector_type(8))) int intx8;

#define B_    128
#define T_    512
#define H_    256
#define H2_   512
#define LIN_  200
#define LINP_ 224
#define G4_   1024
#define SP_   58
#define BT_   (B_*T_)

// ---------- ws layout (bytes) ----------
#define OFF_LS     0UL          // int  [B,T]      262144
#define OFF_LP     262144UL     // int  [B,T]      262144
#define OFF_WID    524288UL     // int  [B,T]      262144
#define OFF_INV    786432UL     // f32  [B,T]      262144
#define OFF_POSW   1212416UL    // f32  [32][200]   25600
#define OFF_WLW    1238016UL    // f32  [8][200]     6400
#define OFF_BIASG  1244416UL    // f32  [1024]       4096
#define OFF_WHH    1248512UL    // fp8  [1024][256] 262144
#define OFF_WIH    1772800UL    // bf16 [1024][224] 458752
#define OFF_WENC   2231552UL    // bf16 [200][512]  204800
#define OFF_COMBW  2436352UL    // bf16 [58][768]    89088
#define OFF_ECW    2525440UL    // bf16 [65536][200] time-major rows (t*128+b)
#define OFF_Z      28739840UL   // bf16 [65536][224] time-major rows
#define OFF_GPERM  58099968UL   // bf16 swizzled [512][32 blk][16 w][4 g][16 u][4 qd]
#define OFF_VBF    192317696UL  // bf16 [65536][768] time-major rows (0:256 hs, 256:768 enc)

__device__ __forceinline__ ushort_t f2bf(float x){
  uint32 u = __float_as_uint(x);
  u += 0x7fffu + ((u >> 16) & 1u);
  return (ushort_t)(u >> 16);
}
__device__ __forceinline__ float bf2f(ushort_t v){
  return __uint_as_float(((uint32)v) << 16);
}
// fast sigmoid/tanh (exp2-based __expf + v_rcp); |err| ~1e-5, way inside bf16
__device__ __forceinline__ float fsig(float x){
  return __builtin_amdgcn_rcpf(1.0f + __expf(-x));
}
__device__ __forceinline__ float ftanh(float x){
  return 1.0f - 2.0f * __builtin_amdgcn_rcpf(1.0f + __expf(2.0f * x));
}

// ---------- fused prologue: scan (blocks 0..127) | encbf (128..2175) | small (2176..) ----------
// The three parts are mutually independent; fusing cuts 9 launches/iter to 7 to
// measure (and harvest) inter-dispatch gap overhead. Branches are block-uniform,
// so the scan-part barriers are safe.
#define PRE_ENC_BLKS 2048
#define PRE_SMALL0   (128 + PRE_ENC_BLKS)
#define PRE_BLKS     (PRE_SMALL0 + 1261)     // ceil(645088/512)=1261
__global__ __launch_bounds__(512) void k_pre(
    const int* __restrict__ sep, const int* __restrict__ pos_ids,
    int* __restrict__ ls, int* __restrict__ lp,
    int* __restrict__ wid, float* __restrict__ inv,
    const float* __restrict__ enc, ushort_t* __restrict__ vbf,
    const float* __restrict__ pos_emb, const float* __restrict__ wl_emb,
    const float* __restrict__ fcW, const float* __restrict__ W_ih,
    const float* __restrict__ W_hh, const float* __restrict__ b_ih,
    const float* __restrict__ b_hh, const float* __restrict__ combW,
    float* __restrict__ posW, float* __restrict__ wlW, float* __restrict__ biasg,
    char* __restrict__ whh8, ushort_t* __restrict__ wih,
    ushort_t* __restrict__ wenc, ushort_t* __restrict__ combwb){
  int bid = blockIdx.x;
  if (bid < 128){
    // ---- scan: last_sep / wordlen / last_pos, Hillis-Steele ----
    int b = bid, t = threadIdx.x;
    __shared__ int sm[512];
    int v = (sep[b*T_ + t] > 0) ? t : 0;
    sm[t] = v;
    __syncthreads();
    #pragma unroll
    for (int off = 1; off < 512; off <<= 1){
      int o = (t >= off) ? sm[t - off] : 0;
      __syncthreads();
      v = (o > v) ? o : v;
      sm[t] = v;
      __syncthreads();
    }
    int l = (t == 0) ? 0 : sm[t - 1];      // last sep strictly before t
    int wlen = t - l;
    int wsv  = (wlen < 1) ? 1 : wlen;
    ls[b*T_ + t]  = l;
    lp[b*T_ + t]  = pos_ids[b*T_ + l];
    wid[b*T_ + t] = (wsv > 7) ? 7 : wsv;
    inv[b*T_ + t] = 1.0f / (float)wsv;
    return;
  }
  if (bid < PRE_SMALL0){
    // ---- enc -> bf16 into vbf[t*128+b][256:768], float4 grid-stride ----
    const long total = (long)BT_ * 128;          // float4 count
    for (long i = (long)(bid - 128) * 512 + threadIdx.x; i < total; i += (long)PRE_ENC_BLKS * 512){
      floatx4 v = ((const floatx4*)enc)[i];
      long row = i >> 7;                         // b*512 + t (enc layout)
      int c4 = (int)(i & 127);
      int b = (int)(row >> 9), t = (int)(row & (T_-1));
      short4v pk;
      pk[0] = (short)f2bf(v[0]); pk[1] = (short)f2bf(v[1]);
      pk[2] = (short)f2bf(v[2]); pk[3] = (short)f2bf(v[3]);
      *(short4v*)(void*)(vbf + ((long)t * B_ + b) * 768 + 256 + c4*4) = pk;
    }
    return;
  }
  // ---- small precomputes / weight conversions ----
  int idx = (bid - PRE_SMALL0) * 512 + threadIdx.x;
  if (idx < 6400){
    int p = idx / 200, l = idx % 200;
    float s = 0.f;
    for (int d = 0; d < 50; d++) s += pos_emb[p*50 + d] * fcW[l*582 + d];
    posW[idx] = s; return;
  }
  idx -= 6400;
  if (idx < 1600){
    int w = idx / 200, l = idx % 200;
    float s = 0.f;
    for (int d = 0; d < 20; d++) s += wl_emb[w*20 + d] * fcW[l*582 + 562 + d];
    wlW[idx] = s; return;
  }
  idx -= 1600;
  if (idx < 1024){ biasg[idx] = b_ih[idx] + b_hh[idx]; return; }
  idx -= 1024;
  if (idx < 262144){
    int p8 = __builtin_amdgcn_cvt_pk_fp8_f32(W_hh[idx], W_hh[idx], 0, false);
    whh8[idx] = (char)(p8 & 0xff);
    return;
  }
  idx -= 262144;
  if (idx < 229376){
    int n = idx / 224, k = idx % 224;
    wih[idx] = (k < 200) ? f2bf(W_ih[n*200 + k]) : (ushort_t)0;
    return;
  }
  idx -= 229376;
  if (idx < 102400){
    int l = idx / 512, c = idx % 512;
    wenc[idx] = f2bf(fcW[l*582 + 50 + c]); return;
  }
  idx -= 102400;
  if (idx < 44544){ combwb[idx] = f2bf(combW[idx]); return; }
}

// ---------- 128x256 8-wave double-buffered bf16 GEMM (mid GEMMs, short K) ----------
// One vmcnt(0)+barrier per K-step, prefetch issued before compute (T3-minimal).
// Linear LDS (gload_lds dst) + XOR swizzle byte^=((row>>1)&3)<<4 applied BOTH sides
// (pre-swizzled source granule + swizzled read addr, rule #21). Harness-verified r9.
template<int EPI>
__global__ __launch_bounds__(512, 2) void k_big(
    const ushort_t* __restrict__ A, long lda,
    const ushort_t* __restrict__ Bm, int K, int Nvalid,
    void* __restrict__ Cout, const float* __restrict__ bias){
  __shared__ __attribute__((aligned(16))) ushort_t As[2][128][32];
  __shared__ __attribute__((aligned(16))) ushort_t Bs[2][256][32];
  int tid  = threadIdx.x;
  int lane = tid & 63, w = tid >> 6;          // 8 waves
  int u = lane & 15, quad = lane >> 4;
  int wm = w >> 2, wn = w & 3;                // 2x4 wave grid, 64x64 per wave
  long m0 = (long)blockIdx.y * 128;
  int  n0 = blockIdx.x * 256;
  int sr = lane >> 2;
  int gp = lane & 3;
  int gl = gp ^ ((sr >> 1) & 3);              // logical granule this lane fetches
  int arow = w*16 + sr;
  const ushort_t* asrc = A + (m0 + arow) * lda + gl*8;
  int brow = w*32 + sr;
  const ushort_t* bsrc0 = Bm + (long)(n0 + brow) * K + gl*8;
  const ushort_t* bsrc1 = Bm + (long)(n0 + brow + 16) * K + gl*8;
  floatx4 acc[4][4] = {};

#define STAGEK(buf, kk) do{ \
    __builtin_amdgcn_global_load_lds( \
        (const __attribute__((address_space(1))) void*)(asrc + (kk)), \
        (__attribute__((address_space(3))) void*)((char*)&As[buf][0][0] + w*1024), 16, 0, 0); \
    __builtin_amdgcn_global_load_lds( \
        (const __attribute__((address_space(1))) void*)(bsrc0 + (kk)), \
        (__attribute__((address_space(3))) void*)((char*)&Bs[buf][0][0] + w*2048), 16, 0, 0); \
    __builtin_amdgcn_global_load_lds( \
        (const __attribute__((address_space(1))) void*)(bsrc1 + (kk)), \
        (__attribute__((address_space(3))) void*)((char*)&Bs[buf][0][0] + w*2048 + 1024), 16, 0, 0); \
  }while(0)

  STAGEK(0, 0);
  asm volatile("s_waitcnt vmcnt(0)\n\ts_barrier" ::: "memory");
  int nk = K >> 5;
  int cur = 0;
  for (int ks = 0; ks < nk; ks++){
    if (ks + 1 < nk) STAGEK(cur ^ 1, (ks + 1) << 5);
    short8 af[4], bfv[4];
    #pragma unroll
    for (int mi = 0; mi < 4; mi++){
      int row = wm*64 + mi*16 + u;
      int off = (row*64 + quad*16) ^ (((row >> 1) & 3) << 4);
      af[mi] = *(const short8*)(const void*)((const char*)&As[cur][0][0] + off);
    }
    #pragma unroll
    for (int ni = 0; ni < 4; ni++){
      int row = wn*64 + ni*16 + u;
      int off = (row*64 + quad*16) ^ (((row >> 1) & 3) << 4);
      bfv[ni] = *(const short8*)(const void*)((const char*)&Bs[cur][0][0] + off);
    }
    #pragma unroll
    for (int mi = 0; mi < 4; mi++)
      #pragma unroll
      for (int ni = 0; ni < 4; ni++)
        acc[mi][ni] = __builtin_amdgcn_mfma_f32_16x16x32_bf16(af[mi], bfv[ni], acc[mi][ni], 0, 0, 0);
    asm volatile("s_waitcnt vmcnt(0)\n\ts_barrier" ::: "memory");
    cur ^= 1;
  }
#undef STAGEK

  if (EPI == 1){
    #pragma unroll
    for (int mi = 0; mi < 4; mi++){
      #pragma unroll
      for (int ni = 0; ni < 4; ni++){
        long mm = m0 + wm*64 + mi*16 + quad*4;   // 4 r's = 4 consecutive b (qd 0..3)
        int n = n0 + wn*64 + ni*16 + u;
        float bv = bias[n];
        int t = (int)(mm >> 7);
        int b = (int)(mm & 127);
        int blk = b >> 2;                         // b % 4 == 0 here
        int g = n >> 8, j = n & 255, ut = j & 15, jt = j >> 4;
        long idx = ((((long)t*32 + blk)*16 + jt)*4 + g)*64 + ut*4;
        short4v pk;
        #pragma unroll
        for (int r = 0; r < 4; r++) pk[r] = (short)f2bf(acc[mi][ni][r] + bv);
        *(short4v*)(void*)((ushort_t*)Cout + idx) = pk;
      }
    }
  } else {
    for (int mi = 0; mi < 4; mi++){
      for (int ni = 0; ni < 4; ni++){
        int n = n0 + wn*64 + ni*16 + u;
        if (n < Nvalid){
          #pragma unroll
          for (int r = 0; r < 4; r++){
            long m = m0 + wm*64 + mi*16 + quad*4 + r;
            ((ushort_t*)Cout)[m * Nvalid + n] = f2bf(acc[mi][ni][r]);
          }
        }
      }
    }
  }
}

// ---------- logits GEMM: BM=256 x BN=64, 8 waves (4x2), dbuf + gload_lds ----------
__global__ __launch_bounds__(512, 2) void k_logit(
    const ushort_t* __restrict__ A,          // vbf [65536][768]
    const ushort_t* __restrict__ Bm,         // combwb [58][768]
    float* __restrict__ Cout, const int* __restrict__ len){
  __shared__ __attribute__((aligned(16))) ushort_t As[2][256][32];
  __shared__ __attribute__((aligned(16))) ushort_t Bs[2][64][32];
  int tid  = threadIdx.x;
  int lane = tid & 63, w = tid >> 6;          // 8 waves
  int u = lane & 15, quad = lane >> 4;
  int wm = w >> 1, wn = w & 1;                // 4x2 wave grid, 64x32 per wave
  long m0 = (long)blockIdx.x * 256;
  int sr = lane >> 2;
  int gp = lane & 3;
  int gl = gp ^ ((sr >> 1) & 3);
  const ushort_t* asrc0 = A + (m0 + w*32 + sr) * 768 + gl*8;
  const ushort_t* asrc1 = A + (m0 + w*32 + 16 + sr) * 768 + gl*8;
  const ushort_t* bsrc  = Bm + (long)(w*16 + sr) * 768 + gl*8;   // waves 0..3 only
  floatx4 acc[4][2] = {};

#define STG(buf, kk) do{ \
    __builtin_amdgcn_global_load_lds( \
        (const __attribute__((address_space(1))) void*)(asrc0 + (kk)), \
        (__attribute__((address_space(3))) void*)((char*)&As[buf][0][0] + w*2048), 16, 0, 0); \
    __builtin_amdgcn_global_load_lds( \
        (const __attribute__((address_space(1))) void*)(asrc1 + (kk)), \
        (__attribute__((address_space(3))) void*)((char*)&As[buf][0][0] + w*2048 + 1024), 16, 0, 0); \
    if (w < 4) __builtin_amdgcn_global_load_lds( \
        (const __attribute__((address_space(1))) void*)(bsrc + (kk)), \
        (__attribute__((address_space(3))) void*)((char*)&Bs[buf][0][0] + w*1024), 16, 0, 0); \
  }while(0)

  STG(0, 0);
  asm volatile("s_waitcnt vmcnt(0)\n\ts_barrier" ::: "memory");
  int cur = 0;
  for (int ks = 0; ks < 24; ks++){
    if (ks + 1 < 24) STG(cur ^ 1, (ks + 1) << 5);
    short8 af[4], bfv[2];
    #pragma unroll
    for (int mi = 0; mi < 4; mi++){
      int row = wm*64 + mi*16 + u;
      int off = (row*64 + quad*16) ^ (((row >> 1) & 3) << 4);
      af[mi] = *(const short8*)(const void*)((const char*)&As[cur][0][0] + off);
    }
    #pragma unroll
    for (int ni = 0; ni < 2; ni++){
      int row = wn*32 + ni*16 + u;
      int off = (row*64 + quad*16) ^ (((row >> 1) & 3) << 4);
      bfv[ni] = *(const short8*)(const void*)((const char*)&Bs[cur][0][0] + off);
    }
    #pragma unroll
    for (int mi = 0; mi < 4; mi++)
      #pragma unroll
      for (int ni = 0; ni < 2; ni++)
        acc[mi][ni] = __builtin_amdgcn_mfma_f32_16x16x32_bf16(af[mi], bfv[ni], acc[mi][ni], 0, 0, 0);
    asm volatile("s_waitcnt vmcnt(0)\n\ts_barrier" ::: "memory");
    cur ^= 1;
  }
#undef STG

  #pragma unroll
  for (int mi = 0; mi < 4; mi++){
    #pragma unroll
    for (int ni = 0; ni < 2; ni++){
      int n = wn*32 + ni*16 + u;
      if (n < SP_){
        #pragma unroll
        for (int r = 0; r < 4; r++){
          long m = m0 + wm*64 + mi*16 + quad*4 + r;
          int t = (int)(m >> 7); int b = (int)(m & 127);
          float o = (t < len[b]) ? acc[mi][ni][r] : 0.0f;
          if (t == 0 && n == 0) o = -1e30f;
          Cout[((long)b * T_ + t) * SP_ + n] = o;
        }
      }
    }
  }
}

// ---------- exclusive cumsum over t, in place on E (bf16, time-major rows) ----------
__global__ __launch_bounds__(256) void k_cum200(ushort_t* __restrict__ E){
  int b = blockIdx.x;
  int c = threadIdx.x;
  if (c >= LIN_) return;
  float acc = 0.f;
  ushort_t* p = E + (long)b * LIN_ + c;      // row (t*128+b)
  const long rs = (long)B_ * LIN_;           // per-t stride
  for (int t0 = 0; t0 < T_; t0 += 16){
    float vv[16];
    #pragma unroll
    for (int i = 0; i < 16; i++) vv[i] = bf2f(p[i*rs]);
    #pragma unroll
    for (int i = 0; i < 16; i++){ p[i*rs] = f2bf(acc); acc += vv[i]; }
    p += 16*rs;
  }
}

// ---------- z = tanh((CW[t]-CW[ls])*inv + posW + wlW + b), t=0 -> 0, pad K to 224 ----------
__global__ __launch_bounds__(256) void k_z(
    const ushort_t* __restrict__ CW, const int* __restrict__ ls, const int* __restrict__ lp,
    const int* __restrict__ wid, const float* __restrict__ inv,
    const float* __restrict__ posW, const float* __restrict__ wlW,
    const float* __restrict__ fcb, ushort_t* __restrict__ zbf){
  int l = threadIdx.x;
  if (l >= LINP_) return;
  float fb = (l < LIN_) ? fcb[l] : 0.f;
  #pragma unroll
  for (int i = 0; i < 8; i++){
    int m = blockIdx.x * 8 + i;       // time-major row t*128+b
    int t = m >> 7;
    int b = m & 127;
    int ar = b * T_ + t;              // b-major aux index
    ushort_t o = 0;
    if (t != 0 && l < LIN_){
      int lsv = ls[ar];
      float x = bf2f(CW[(long)m * LIN_ + l]) - bf2f(CW[((long)lsv * B_ + b) * LIN_ + l]);
      x = x * inv[ar] + posW[lp[ar]*LIN_ + l] + wlW[wid[ar]*LIN_ + l] + fb;
      o = f2bf(ftanh(x));
    }
    zbf[(long)m * LINP_ + l] = o;
  }
}

// ---------- LSTM recurrence: 32 blocks x 1024 threads, NB=4 batches/block ----------
// Plateau form (438us). Per-step budget = 1104cyc MFMA issue (decomposition-
// invariant: per-SIMD MFMA count fixed by gate-rows x K / SIMDs for any
// self-contained block split) + ~950cyc serial h-dependency chain. Scheduling
// levers (setprio, dump ring, packed h4, split, interleave) measured neutral.
// Cross-block gate-split rejected by arithmetic: replaces 50cyc LDS barrier
// with ~1000cyc device-scope L3 round trip per step.
__global__ __launch_bounds__(1024, 4) void k_rec(
    const ushort_t* __restrict__ Gperm, const char* __restrict__ whh8,
    ushort_t* __restrict__ vbf){
  int blk  = blockIdx.x;                      // 0..31: batches blk*4 .. blk*4+3
  int tid  = threadIdx.x;
  int lane = tid & 63, w = tid >> 6;          // w in [0,16): hidden j-tile
  int u = lane & 15, quad = lane >> 4;        // quad = local batch index
  __shared__ __attribute__((aligned(16))) char h8[2][16][272];   // row stride 272
  for (int i = tid; i < (int)(sizeof(h8)/4); i += 1024) ((int*)h8)[i] = 0;

  // W_hh fp8 B-fragments (MX K=128): gate g, cols w*16+u; pinned in VGPRs.
  intx8 wfx[4][2];
  #pragma unroll
  for (int g = 0; g < 4; g++){
    int grow = g*256 + w*16 + u;
    #pragma unroll
    for (int kc = 0; kc < 2; kc++){
      intx8 v = *(const intx8*)(const void*)(whh8 + (long)grow*256 + kc*128 + quad*32);
      asm volatile("" : "+v"(v));
      wfx[g][kc] = v;
    }
  }
  float c_reg = 0.f;
  floatx4 acc[4] = {};   // element 0 rebuilt each step; elements 1..3 stay 0 forever

  // Gperm[t][blk][w][g][u][qd]: lane (quad,u) reads gate g at g*64 + u*4 + quad
  const ushort_t* gp0 = Gperm + ((long)blk*16 + w)*256 + (long)u*4 + quad;
  ushort_t gb[4];
  #pragma unroll
  for (int g = 0; g < 4; g++) gb[g] = gp0[g*64];

  for (int t = 0; t < T_; t++){
    #pragma unroll
    for (int g = 0; g < 4; g++) acc[g][0] = bf2f(gb[g]);
    // lgkm-only barrier: h8 write(t-1) -> read(t) edge; vbf store + Gperm loads
    // stay in flight across the barrier (T4: never drain vmcnt in the loop).
    asm volatile("s_waitcnt lgkmcnt(0)\n\ts_barrier" ::: "memory");
    intx8 af0 = *(const intx8*)(const void*)&h8[t & 1][u][quad*32];
    intx8 af1 = *(const intx8*)(const void*)&h8[t & 1][u][128 + quad*32];
    // EARLY: coalesced vbf dump of h(t-1) (independent of MFMAs; VMEM pipe)
    if (t && w < 4){
      ushort_t* vrow = vbf + ((long)(t-1) * B_ + blk*4 + w) * 768;
      uint32 p = *(const uint32*)(const void*)&h8[t & 1][4*w][lane*4];
      float2v lo = __builtin_amdgcn_cvt_pk_f32_fp8(p, false);
      float2v hi = __builtin_amdgcn_cvt_pk_f32_fp8(p, true);
      short4v pk;
      pk[0] = (short)f2bf(lo[0]); pk[1] = (short)f2bf(lo[1]);
      pk[2] = (short)f2bf(hi[0]); pk[3] = (short)f2bf(hi[1]);
      *(short4v*)(void*)&vrow[lane*4] = pk;
    }
    // EARLY: prefetch next Gperm values (hides HBM latency under MFMAs)
    if (t + 1 < T_){
      const ushort_t* gp = gp0 + (long)(t+1)*131072;
      #pragma unroll
      for (int g = 0; g < 4; g++) gb[g] = gp[g*64];
    }
    // gates i,f
    acc[0] = __builtin_amdgcn_mfma_scale_f32_16x16x128_f8f6f4(
        af0, wfx[0][0], acc[0], 0, 0, 0, 0x7F7F7F7F, 0, 0x7F7F7F7F);
    acc[0] = __builtin_amdgcn_mfma_scale_f32_16x16x128_f8f6f4(
        af1, wfx[0][1], acc[0], 0, 0, 0, 0x7F7F7F7F, 0, 0x7F7F7F7F);
    acc[1] = __builtin_amdgcn_mfma_scale_f32_16x16x128_f8f6f4(
        af0, wfx[1][0], acc[1], 0, 0, 0, 0x7F7F7F7F, 0, 0x7F7F7F7F);
    acc[1] = __builtin_amdgcn_mfma_scale_f32_16x16x128_f8f6f4(
        af1, wfx[1][1], acc[1], 0, 0, 0, 0x7F7F7F7F, 0, 0x7F7F7F7F);
    // i,f activations co-issue on VALU while g,o MFMAs occupy the matrix pipe
    float iv = fsig (acc[0][0]);
    float fv = fsig (acc[1][0]);
    // gates g,o
    acc[2] = __builtin_amdgcn_mfma_scale_f32_16x16x128_f8f6f4(
        af0, wfx[2][0], acc[2], 0, 0, 0, 0x7F7F7F7F, 0, 0x7F7F7F7F);
    acc[2] = __builtin_amdgcn_mfma_scale_f32_16x16x128_f8f6f4(
        af1, wfx[2][1], acc[2], 0, 0, 0, 0x7F7F7F7F, 0, 0x7F7F7F7F);
    acc[3] = __builtin_amdgcn_mfma_scale_f32_16x16x128_f8f6f4(
        af0, wfx[3][0], acc[3], 0, 0, 0, 0x7F7F7F7F, 0, 0x7F7F7F7F);
    acc[3] = __builtin_amdgcn_mfma_scale_f32_16x16x128_f8f6f4(
        af1, wfx[3][1], acc[3], 0, 0, 0, 0x7F7F7F7F, 0, 0x7F7F7F7F);
    float gv = ftanh(acc[2][0]);
    float ov = fsig (acc[3][0]);
    float c  = fv * c_reg + iv * gv;
    c_reg = c;
    float h  = ov * ftanh(c);
    int p8 = __builtin_amdgcn_cvt_pk_fp8_f32(h, h, 0, false);
    h8[(t+1)&1][quad*4][w*16 + u] = (char)(p8 & 0xff);
  }
  __syncthreads();
  // final dump: h(511) lives in h8[0]
  if (w < 4){
    ushort_t* vrow = vbf + ((long)(T_-1) * B_ + blk*4 + w) * 768;
    uint32 p = *(const uint32*)(const void*)&h8[0][4*w][lane*4];
    float2v lo = __builtin_amdgcn_cvt_pk_f32_fp8(p, false);
    float2v hi = __builtin_amdgcn_cvt_pk_f32_fp8(p, true);
    short4v pk;
    pk[0] = (short)f2bf(lo[0]); pk[1] = (short)f2bf(lo[1]);
    pk[2] = (short)f2bf(hi[0]); pk[3] = (short)f2bf(hi[1]);
    *(short4v*)(void*)&vrow[lane*4] = pk;
  }
}

extern "C" void kernel_launch(void* const* d_in, const int* in_sizes, int n_in,
                              void* d_out, int out_size, void* d_ws, size_t ws_size,
                              hipStream_t stream){
  (void)in_sizes; (void)n_in; (void)out_size; (void)ws_size;
  const float* enc     = (const float*)d_in[0];
  const int*   sep     = (const int*)  d_in[1];
  const int*   pos_ids = (const int*)  d_in[2];
  const int*   len     = (const int*)  d_in[3];
  const float* pos_emb = (const float*)d_in[4];
  const float* wl_emb  = (const float*)d_in[5];
  const float* fcW     = (const float*)d_in[6];
  const float* fcb     = (const float*)d_in[7];
  const float* W_ih    = (const float*)d_in[8];
  const float* W_hh    = (const float*)d_in[9];
  const float* b_ih    = (const float*)d_in[10];
  const float* b_hh    = (const float*)d_in[11];
  const float* combW   = (const float*)d_in[12];

  char* ws = (char*)d_ws;
  int*      ls    = (int*)     (ws + OFF_LS);
  int*      lp    = (int*)     (ws + OFF_LP);
  int*      wid   = (int*)     (ws + OFF_WID);
  float*    inv   = (float*)   (ws + OFF_INV);
  float*    posW  = (float*)   (ws + OFF_POSW);
  float*    wlW   = (float*)   (ws + OFF_WLW);
  float*    biasg = (float*)   (ws + OFF_BIASG);
  char*     whh8  = (char*)    (ws + OFF_WHH);
  ushort_t* wih   = (ushort_t*)(ws + OFF_WIH);
  ushort_t* wenc  = (ushort_t*)(ws + OFF_WENC);
  ushort_t* combwb= (ushort_t*)(ws + OFF_COMBW);
  ushort_t* ecw   = (ushort_t*)(ws + OFF_ECW);
  ushort_t* zbf   = (ushort_t*)(ws + OFF_Z);
  ushort_t* gperm = (ushort_t*)(ws + OFF_GPERM);
  ushort_t* vbf   = (ushort_t*)(ws + OFF_VBF);

  // fused prologue: scan | enc->bf16 | small precomputes (was 3 launches)
  k_pre<<<PRE_BLKS, 512, 0, stream>>>(sep, pos_ids, ls, lp, wid, inv,
                                      enc, vbf,
                                      pos_emb, wl_emb, fcW, W_ih, W_hh, b_ih, b_hh, combW,
                                      posW, wlW, biasg, whh8, wih, wenc, combwb);
  // E = enc @ Wenc^T  (128x256 dbuf tile; N=200 in one 256 tile)
  k_big<0><<<dim3(1, BT_/128), 512, 0, stream>>>(vbf + 256, 768L, wenc, 512, LIN_, ecw, nullptr);
  // exclusive cumsum over t (in place) -> CW
  k_cum200<<<B_, 256, 0, stream>>>(ecw);
  // z = tanh(...) (8 rows per block)
  k_z<<<BT_/8, 256, 0, stream>>>(ecw, ls, lp, wid, inv, posW, wlW, fcb, zbf);
  // Gperm = z @ W_ih^T + biases (128x256 dbuf tile, Gperm-swizzled epilogue)
  k_big<1><<<dim3(4, BT_/128), 512, 0, stream>>>(zbf, (long)LINP_, wih, LINP_, G4_, gperm, biasg);
  // LSTM recurrence (single kernel, plateau form)
  k_rec<<<32, 1024, 0, stream>>>(gperm, whh8, vbf);
  // logits = [hs, enc] @ combine_W^T (256x64 dbuf tile), masked, b-major output
  k_logit<<<BT_/256, 512, 0, stream>>>(vbf, combwb, (float*)d_out, len);
}